// Round 2
// baseline (744.481 us; speedup 1.0000x reference)
//
#include <hip/hip_runtime.h>
#include <hip/hip_bf16.h>

// Problem constants (from reference setup_inputs)
constexpr int NB = 32;      // batch
constexpr int NN = 4096;    // nodes
constexpr int NE = 16384;   // edges
constexpr int NOUT_PAD = 2432;  // 32*(64 v1) + 32*(12 adv) partial row size

typedef __attribute__((ext_vector_type(8))) short short8;    // 8 bf16 = 4 VGPRs (MFMA A/B frag)
typedef __attribute__((ext_vector_type(4))) float floatx4;   // MFMA C/D frag

__device__ __forceinline__ float relu_(float x) { return fmaxf(x, 0.0f); }
__device__ __forceinline__ unsigned short bf16_(float x) {
  __hip_bfloat16 h = __float2bfloat16(x);
  return __builtin_bit_cast(unsigned short, h);
}

// ---------------------------------------------------------------- init
__global__ void k_init(float* deg, int* cnt, int* fill) {
  int i = blockIdx.x * 256 + threadIdx.x;
  if (i < NN) { deg[i] = 1.0f; cnt[i] = 0; fill[i] = 0; }  // deg starts at self-loop weight 1
}

// ---------------------------------------------------------------- edge pass 1: degree + counts
__global__ void k_edge1(const int* __restrict__ ei, const float* __restrict__ ew,
                        float* deg, int* cnt) {
  int e = blockIdx.x * 256 + threadIdx.x;
  if (e < NE) {
    int d = ei[NE + e];
    atomicAdd(&deg[d], ew[e]);
    atomicAdd(&cnt[d], 1);
  }
}

// ---------------------------------------------------------------- scan: csr offsets + dinv
__global__ void k_scan(const float* __restrict__ deg, float* __restrict__ dinv,
                       const int* __restrict__ cnt, int* __restrict__ csr_off) {
  __shared__ int sd[1024];
  int t = threadIdx.x;
  int base = t * 4;
  int c0 = cnt[base], c1 = cnt[base+1], c2 = cnt[base+2], c3 = cnt[base+3];
  int s = c0 + c1 + c2 + c3;
  sd[t] = s;
  __syncthreads();
  for (int off = 1; off < 1024; off <<= 1) {
    int v = (t >= off) ? sd[t - off] : 0;
    __syncthreads();
    sd[t] += v;
    __syncthreads();
  }
  int excl = sd[t] - s;
  csr_off[base]     = excl;
  csr_off[base + 1] = excl + c0;
  csr_off[base + 2] = excl + c0 + c1;
  csr_off[base + 3] = excl + c0 + c1 + c2;
  if (t == 1023) csr_off[4096] = sd[1023];
  for (int i = base; i < base + 4; ++i) dinv[i] = rsqrtf(deg[i]);
}

// ---------------------------------------------------------------- edge pass 2: fill CSR with normalized weights
__global__ void k_fill(const int* __restrict__ ei, const float* __restrict__ ew,
                       const float* __restrict__ dinv, const int* __restrict__ csr_off,
                       int* fill, int* __restrict__ csr_src, float* __restrict__ csr_w) {
  int e = blockIdx.x * 256 + threadIdx.x;
  if (e < NE) {
    int s = ei[e], d = ei[NE + e];
    float wn = ew[e] * dinv[s] * dinv[d];
    int p = csr_off[d] + atomicAdd(&fill[d], 1);
    csr_src[p] = s;
    csr_w[p] = wn;
  }
}

// ---------------------------------------------------------------- W2T[j][c] = bf16(W2[c][j])
__global__ void k_prep(const float* __restrict__ W2, unsigned short* __restrict__ W2T) {
  int idx = blockIdx.x * 256 + threadIdx.x;  // 32768 = 256 j * 128 c
  int j = idx >> 7, c = idx & 127;
  W2T[idx] = bf16_(W2[c * 256 + j]);
}

// ---------------------------------------------------------------- g0 = agg(x), 16 features
__global__ __launch_bounds__(256) void k_agg16(
    const float* __restrict__ x, const float* __restrict__ dinv,
    const int* __restrict__ csr_off, const int* __restrict__ csr_src,
    const float* __restrict__ csr_w, float* __restrict__ g0) {
  int b = blockIdx.y;
  int nn = threadIdx.x >> 4, f = threadIdx.x & 15;
  int n = blockIdx.x * 16 + nn;
  float di = dinv[n];
  size_t base = ((size_t)b * NN + n) * 16;
  float acc = x[base + f] * di * di;  // self term: h/deg
  int e0 = csr_off[n], e1 = csr_off[n + 1];
  for (int e = e0; e < e1; ++e)
    acc = fmaf(csr_w[e], x[((size_t)b * NN + csr_src[e]) * 16 + f], acc);
  g0[base + f] = acc;
}

// ---------------------------------------------------------------- h1 = relu(g0 @ W1 + b1)   [16 -> 128]
__global__ __launch_bounds__(256) void k_gemm1(
    const float* __restrict__ g0, const float* __restrict__ W1,
    const float* __restrict__ b1, float* __restrict__ h1) {
  __shared__ float W1s[16 * 128];
  __shared__ float g0s[256];
  int b = blockIdx.y, tile = blockIdx.x, t = threadIdx.x;
  for (int i = t; i < 2048; i += 256) W1s[i] = W1[i];
  g0s[t] = g0[((size_t)b * NN + tile * 16) * 16 + t];
  __syncthreads();
  int k = t & 127, ng = t >> 7;
  float wreg[16];
#pragma unroll
  for (int f = 0; f < 16; ++f) wreg[f] = W1s[f * 128 + k];
  float bias = b1[k];
#pragma unroll
  for (int nn = 0; nn < 8; ++nn) {
    int nl = ng * 8 + nn;
    float acc = bias;
#pragma unroll
    for (int f = 0; f < 16; ++f) acc = fmaf(g0s[nl * 16 + f], wreg[f], acc);
    h1[((size_t)b * NN + tile * 16 + nl) * 128 + k] = relu_(acc);
  }
}

// ---------------------------------------------------------------- g1b[n][b][c] (bf16) = agg(h1), fp32 accumulate
__global__ __launch_bounds__(256) void k_agg128(
    const float* __restrict__ h1, const float* __restrict__ dinv,
    const int* __restrict__ csr_off, const int* __restrict__ csr_src,
    const float* __restrict__ csr_w, unsigned short* __restrict__ g1b) {
  int b = blockIdx.y;
  int nn = threadIdx.x >> 7, c = threadIdx.x & 127;
  int n = blockIdx.x * 2 + nn;
  float di = dinv[n];
  float acc = h1[((size_t)b * NN + n) * 128 + c] * di * di;
  int e0 = csr_off[n], e1 = csr_off[n + 1];
  for (int e = e0; e < e1; ++e)
    acc = fmaf(csr_w[e], h1[((size_t)b * NN + csr_src[e]) * 128 + c], acc);
  g1b[((size_t)n * NB + b) * 128 + c] = bf16_(acc);
}

// ---------------------------------------------------------------- h2T[f][b] = relu(g1 @ W2 + b2) via bf16 MFMA
// C[m=j][n=b] = sum_c A[j][c]*B[c][b]; A = W2T (regs, whole block), B = g1 node tile (LDS).
// block = 8 nodes, 256 thr = 4 waves; wave w owns mtiles 4w..4w+3 (j = 64w..64w+63).
// 16x16x32 frag layout: A[m=lane&15][k=quad*8+j], B[k=quad*8+j][n=lane&15],
// C col=lane&15 (b), row=quad*4+reg (j). LDS rows padded to 136 ushorts (16B-aligned, even bank spread).
__global__ __launch_bounds__(256) void k_gemm2b(
    const unsigned short* __restrict__ g1b, const unsigned short* __restrict__ W2T,
    const float* __restrict__ b2, float* __restrict__ h2T) {
  __shared__ unsigned short g1s[32][136];
  int t = threadIdx.x;
  int l = t & 63, w = t >> 6;
  int r = l & 15, ql = l >> 4;
  int n0 = blockIdx.x * 8;
  // A fragments: held in registers for the whole block (16 frags = 64 VGPRs)
  short8 afr[4][4];
#pragma unroll
  for (int mt = 0; mt < 4; ++mt)
#pragma unroll
    for (int kt = 0; kt < 4; ++kt)
      afr[mt][kt] = *(const short8*)&W2T[((w * 4 + mt) * 16 + r) * 128 + kt * 32 + ql * 8];
  // bias per (mt, reg)
  float bias[4][4];
#pragma unroll
  for (int mt = 0; mt < 4; ++mt)
#pragma unroll
    for (int rr = 0; rr < 4; ++rr)
      bias[mt][rr] = b2[(w * 4 + mt) * 16 + ql * 4 + rr];
  // prefetch node 0's g1 tile (8 KB = 512 x 16B chunks; thread t takes chunks t, t+256)
  uint4 pf0, pf1;
  {
    const uint4* src = (const uint4*)(g1b + (size_t)n0 * NB * 128);
    pf0 = src[t]; pf1 = src[t + 256];
  }
  for (int i = 0; i < 8; ++i) {
    __syncthreads();  // previous iteration's LDS readers done
    *(uint4*)&g1s[t >> 4][(t & 15) * 8] = pf0;
    {
      int i1 = t + 256;
      *(uint4*)&g1s[i1 >> 4][(i1 & 15) * 8] = pf1;
    }
    if (i + 1 < 8) {  // prefetch next node while this one computes
      const uint4* src = (const uint4*)(g1b + (size_t)(n0 + i + 1) * NB * 128);
      pf0 = src[t]; pf1 = src[t + 256];
    }
    __syncthreads();
    short8 bfr[2][4];
#pragma unroll
    for (int nt = 0; nt < 2; ++nt)
#pragma unroll
      for (int kt = 0; kt < 4; ++kt)
        bfr[nt][kt] = *(const short8*)&g1s[nt * 16 + r][kt * 32 + ql * 8];
    floatx4 acc[4][2];
#pragma unroll
    for (int mt = 0; mt < 4; ++mt)
#pragma unroll
      for (int nt = 0; nt < 2; ++nt) {
        floatx4 a = {0.0f, 0.0f, 0.0f, 0.0f};
#pragma unroll
        for (int kt = 0; kt < 4; ++kt)
          a = __builtin_amdgcn_mfma_f32_16x16x32_bf16(afr[mt][kt], bfr[nt][kt], a, 0, 0, 0);
        acc[mt][nt] = a;
      }
    size_t nodebase = (size_t)(n0 + i) * 256;
#pragma unroll
    for (int mt = 0; mt < 4; ++mt) {
#pragma unroll
      for (int rr = 0; rr < 4; ++rr) {
        int j = (w * 4 + mt) * 16 + ql * 4 + rr;
        float* dst = h2T + (nodebase + j) * 32 + r;
        dst[0]  = relu_(acc[mt][0][rr] + bias[mt][rr]);
        dst[16] = relu_(acc[mt][1][rr] + bias[mt][rr]);
      }
    }
  }
}

// ---------------------------------------------------------------- head v2: per-block (256 f) partials of feat@v1W, feat@advW
// Lane decomposition kills the LDS-broadcast bottleneck of v1:
//   lane l -> bgrp = l&7 (4 batches: bgrp*4..+3), c = l>>3 (8 v1 cols: c*8..+7, 2 adv cols: c*2..+1 for c<6).
// Per feature row: ONE ds_read_b128 (8 distinct 16B chunks, same-address broadcast within chunk = conflict-free)
// + 2 coalesced dwordx4 of v1W row + 1 dwordx2 of advW row + 40 fma.
// Old layout issued 8 b128 broadcasts + 64 fma (half on zero adv weights) per row -> LDS-issue bound (164 us).
__global__ __launch_bounds__(256) void k_head(
    const float* __restrict__ h2T, const float* __restrict__ v1W,
    const float* __restrict__ advW, float* __restrict__ P) {
  __shared__ float s[8192];  // feat staging, then cross-wave reduction
  int t = threadIdx.x;
  size_t f0 = (size_t)blockIdx.x * 256;
  const float4* src = (const float4*)(h2T + f0 * 32);
  float4* dst = (float4*)s;
#pragma unroll
  for (int i = 0; i < 8; ++i) dst[t + 256 * i] = src[t + 256 * i];
  __syncthreads();
  int l = t & 63, w = t >> 6;
  int bgrp = l & 7, c = l >> 3;
  const float amask = (c < 6) ? 1.0f : 0.0f;
  int ac = (c < 6) ? c * 2 : 0;  // adv col base (c>=6 loads col 0, masked to 0)
  float accv[8][4];   // [k: col c*8+k][q: batch bgrp*4+q]
  float acca[2][4];   // [k: col c*2+k][q]
#pragma unroll
  for (int k = 0; k < 8; ++k)
#pragma unroll
    for (int q = 0; q < 4; ++q) accv[k][q] = 0.0f;
#pragma unroll
  for (int k = 0; k < 2; ++k)
#pragma unroll
    for (int q = 0; q < 4; ++q) acca[k][q] = 0.0f;
  const float* v1p  = v1W  + (f0 + (size_t)w * 64) * 64 + c * 8;
  const float* advp = advW + (f0 + (size_t)w * 64) * 12 + ac;
#pragma unroll 2
  for (int f = 0; f < 64; ++f) {
    float4 h4 = *(const float4*)&s[(w * 64 + f) * 32 + bgrp * 4];
    float4 wv0 = *(const float4*)(v1p + (size_t)f * 64);
    float4 wv1 = *(const float4*)(v1p + (size_t)f * 64 + 4);
    float2 wa2 = *(const float2*)(advp + (size_t)f * 12);
    float hq[4] = {h4.x, h4.y, h4.z, h4.w};
    float wv[8] = {wv0.x, wv0.y, wv0.z, wv0.w, wv1.x, wv1.y, wv1.z, wv1.w};
    float wa[2] = {wa2.x * amask, wa2.y * amask};
#pragma unroll
    for (int k = 0; k < 8; ++k)
#pragma unroll
      for (int q = 0; q < 4; ++q)
        accv[k][q] = fmaf(hq[q], wv[k], accv[k][q]);
#pragma unroll
    for (int k = 0; k < 2; ++k)
#pragma unroll
      for (int q = 0; q < 4; ++q)
        acca[k][q] = fmaf(hq[q], wa[k], acca[k][q]);
  }
  float* Pb = P + (size_t)blockIdx.x * NOUT_PAD;
  __syncthreads();
  // v1 partials: cell o = b*64 + col
#pragma unroll
  for (int k = 0; k < 8; ++k)
#pragma unroll
    for (int q = 0; q < 4; ++q)
      s[w * 2048 + (bgrp * 4 + q) * 64 + c * 8 + k] = accv[k][q];
  __syncthreads();
  for (int o = t; o < 2048; o += 256)
    Pb[o] = s[o] + s[2048 + o] + s[4096 + o] + s[6144 + o];
  __syncthreads();
  if (c < 6) {
#pragma unroll
    for (int k = 0; k < 2; ++k)
#pragma unroll
      for (int q = 0; q < 4; ++q)
        s[w * 384 + (bgrp * 4 + q) * 12 + c * 2 + k] = acca[k][q];
  }
  __syncthreads();
  for (int o = t; o < 384; o += 256)
    Pb[2048 + o] = s[o] + s[384 + o] + s[768 + o] + s[1152 + o];
}

// ---------------------------------------------------------------- reduce stage 1: 4096 -> 64 rows
__global__ __launch_bounds__(256) void k_red1(const float* __restrict__ P,
                                              float* __restrict__ P1) {
  int r = blockIdx.x, t = threadIdx.x;
  const float* p = P + (size_t)r * 64 * NOUT_PAD;
  for (int o = t; o < NOUT_PAD; o += 256) {
    float sum = 0.0f;
    for (int k = 0; k < 64; ++k) sum += p[(size_t)k * NOUT_PAD + o];
    P1[r * NOUT_PAD + o] = sum;
  }
}

// ---------------------------------------------------------------- reduce stage 2: 64 -> 1
__global__ __launch_bounds__(256) void k_red2(const float* __restrict__ P1,
                                              float* __restrict__ S) {
  int o = blockIdx.x * 256 + threadIdx.x;
  if (o >= NOUT_PAD) return;
  float sum = 0.0f;
  for (int r = 0; r < 64; ++r) sum += P1[(size_t)r * NOUT_PAD + o];
  S[o] = sum;
}

// ---------------------------------------------------------------- final MLP + dueling combine
__global__ void k_final(const float* __restrict__ S,
                        const float* __restrict__ v1b, const float* __restrict__ v2W,
                        const float* __restrict__ v2b, const float* __restrict__ v3W,
                        const float* __restrict__ v3b, const float* __restrict__ advb,
                        float* __restrict__ out) {
  int b = blockIdx.x, t = threadIdx.x;
  __shared__ float v1s[64], v2s[64], as_[12];
  __shared__ float v3s;
  v1s[t] = relu_(S[b * 64 + t] + v1b[t]);
  if (t < 12) as_[t] = relu_(S[2048 + b * 12 + t] + advb[t]);
  __syncthreads();
  float acc = v2b[t];
  for (int k = 0; k < 64; ++k) acc = fmaf(v1s[k], v2W[k * 64 + t], acc);
  v2s[t] = relu_(acc);
  __syncthreads();
  if (t == 0) {
    float v3 = v3b[0];
    for (int j = 0; j < 64; ++j) v3 = fmaf(v2s[j], v3W[j], v3);
    v3s = v3;
  }
  __syncthreads();
  if (t < 12) {
    int h = t >> 2;
    float m = 0.25f * (as_[h * 4] + as_[h * 4 + 1] + as_[h * 4 + 2] + as_[h * 4 + 3]);
    out[b * 12 + t] = v3s + as_[t] - m;
  }
}

// ================================================================ launcher
extern "C" void kernel_launch(void* const* d_in, const int* in_sizes, int n_in,
                              void* d_out, int out_size, void* d_ws, size_t ws_size,
                              hipStream_t stream) {
  (void)in_sizes; (void)n_in; (void)out_size; (void)ws_size;
  const float* x    = (const float*)d_in[0];
  const int*   ei   = (const int*)d_in[1];
  const float* ew   = (const float*)d_in[2];
  const float* W1   = (const float*)d_in[3];
  const float* b1   = (const float*)d_in[4];
  const float* W2   = (const float*)d_in[5];
  const float* b2   = (const float*)d_in[6];
  const float* advW = (const float*)d_in[7];
  const float* advb = (const float*)d_in[8];
  const float* v1W  = (const float*)d_in[9];
  const float* v1b  = (const float*)d_in[10];
  const float* v2W  = (const float*)d_in[11];
  const float* v2b  = (const float*)d_in[12];
  const float* v3W  = (const float*)d_in[13];
  const float* v3b  = (const float*)d_in[14];
  float* out = (float*)d_out;

  const size_t MB = 1024 * 1024;
  char* w8 = (char*)d_ws;
  // small region [0, 4 MB)
  float* deg     = (float*)w8;                 // 4096
  float* dinv    = deg + 4096;                 // 4096
  int*   csr_off = (int*)(dinv + 4096);        // 4097 (padded to 4352)
  int*   cnt     = csr_off + 4352;             // 4096
  int*   fill    = cnt + 4096;                 // 4096
  int*   csr_src = fill + 4096;                // 16384
  float* csr_w   = (float*)(csr_src + NE);     // 16384
  float* S       = csr_w + NE;                 // 2432
  unsigned short* W2T = (unsigned short*)(S + 2432);  // 32768 ushorts
  // big buffers with lifetime-based overlays:
  //   h1  [4,68)    gemm1 -> agg128
  //   g0  [68,76)   agg16 -> gemm1
  //   h2T [4,132)   gemm2b (h1,g0 dead) -> head
  //   g1b [132,165) agg128 -> gemm2b  (bf16, 32 MB)
  //   P   [165,204) head -> red1
  //   P1  [204,205) red1 -> red2
  float* h1           = (float*)(w8 + 4 * MB);
  float* g0           = (float*)(w8 + 68 * MB);
  float* h2T          = (float*)(w8 + 4 * MB);
  unsigned short* g1b = (unsigned short*)(w8 + 132 * MB);
  float* P            = (float*)(w8 + 165 * MB);
  float* P1           = (float*)(w8 + 204 * MB);

  k_init  <<<16, 256, 0, stream>>>(deg, cnt, fill);
  k_edge1 <<<64, 256, 0, stream>>>(ei, ew, deg, cnt);
  k_scan  <<<1, 1024, 0, stream>>>(deg, dinv, cnt, csr_off);
  k_fill  <<<64, 256, 0, stream>>>(ei, ew, dinv, csr_off, fill, csr_src, csr_w);
  k_prep  <<<128, 256, 0, stream>>>(W2, W2T);
  k_agg16 <<<dim3(NN / 16, NB), 256, 0, stream>>>(x, dinv, csr_off, csr_src, csr_w, g0);
  k_gemm1 <<<dim3(NN / 16, NB), 256, 0, stream>>>(g0, W1, b1, h1);
  k_agg128<<<dim3(NN / 2, NB), 256, 0, stream>>>(h1, dinv, csr_off, csr_src, csr_w, g1b);
  k_gemm2b<<<NN / 8, 256, 0, stream>>>(g1b, W2T, b2, h2T);
  k_head  <<<NN, 256, 0, stream>>>(h2T, v1W, advW, P);
  k_red1  <<<64, 256, 0, stream>>>(P, P1);
  k_red2  <<<10, 256, 0, stream>>>(P1, S);
  k_final <<<NB, 64, 0, stream>>>(S, v1b, v2W, v2b, v3W, v3b, advb, out);
}